// Round 3
// baseline (3451.907 us; speedup 1.0000x reference)
//
#include <hip/hip_runtime.h>
#include <stdint.h>

// MultiHeadAttention: B=4, S=2048, D_MODEL=512, H=8, dk=dv=64.
// ALL tensors fp32 (per reference setup_inputs: jnp.float32). fp32 math.
// Pipeline: LN(x) -> proj GEMM (head-split) per input -> fused scores/softmax/attn-write/PV -> LN -> fc GEMM.
// Round 3: dtype fix bf16 -> fp32 (NaN root cause: fp32 buffers read as bf16 halves).

#define S_LEN 2048
#define DM 512
#define NH 8
#define DK 64

// -------- LayerNorm: one wave per row of 512, 4 rows per block --------
__global__ __launch_bounds__(256) void ln_kernel(const float* __restrict__ src,
    float* __restrict__ dst, const float* __restrict__ gw,
    const float* __restrict__ bw) {
  const int lane = threadIdx.x & 63;
  const int row  = blockIdx.x * 4 + (threadIdx.x >> 6);
  const size_t off = (size_t)row * DM + lane * 8;
  float4 a = *reinterpret_cast<const float4*>(src + off);
  float4 b = *reinterpret_cast<const float4*>(src + off + 4);
  float v[8] = {a.x, a.y, a.z, a.w, b.x, b.y, b.z, b.w};
  float s = 0.f, sq = 0.f;
#pragma unroll
  for (int i = 0; i < 8; i++) { s += v[i]; sq += v[i] * v[i]; }
#pragma unroll
  for (int m = 32; m > 0; m >>= 1) { s += __shfl_xor(s, m, 64); sq += __shfl_xor(sq, m, 64); }
  const float mu = s * (1.f / DM);
  const float var = sq * (1.f / DM) - mu * mu;
  const float rstd = rsqrtf(var + 1e-5f);
  float4 g0 = *reinterpret_cast<const float4*>(gw + lane * 8);
  float4 g1 = *reinterpret_cast<const float4*>(gw + lane * 8 + 4);
  float4 b0 = *reinterpret_cast<const float4*>(bw + lane * 8);
  float4 b1 = *reinterpret_cast<const float4*>(bw + lane * 8 + 4);
  float g[8] = {g0.x, g0.y, g0.z, g0.w, g1.x, g1.y, g1.z, g1.w};
  float bb[8] = {b0.x, b0.y, b0.z, b0.w, b1.x, b1.y, b1.z, b1.w};
  float o[8];
#pragma unroll
  for (int i = 0; i < 8; i++) o[i] = (v[i] - mu) * rstd * g[i] + bb[i];
  *reinterpret_cast<float4*>(dst + off)     = make_float4(o[0], o[1], o[2], o[3]);
  *reinterpret_cast<float4*>(dst + off + 4) = make_float4(o[4], o[5], o[6], o[7]);
}

// -------- GEMM: C[r,o] = sum_k A[r,k] * W[o,k]  (torch Linear, B^T form) --------
// A: [M,512] fp32 row-major, W: [512,512] fp32 row-major [out,in].
// split=1: write head-split [B][H][S][64]; split=0: flat [M][512].
__global__ __launch_bounds__(256) void gemm_bt(const float* __restrict__ A,
    const float* __restrict__ W, float* __restrict__ C, int split) {
  __shared__ float As[16][68];
  __shared__ float Bs[16][68];
  const int t = threadIdx.x;
  const int tx = t & 15, ty = t >> 4;
  const int m0 = blockIdx.x * 64, n0 = blockIdx.y * 64;
  float acc[4][4] = {};
  const int lm = t >> 2;        // 0..63 row within tile
  const int lk = (t & 3) * 4;   // 0,4,8,12
  for (int k0 = 0; k0 < DM; k0 += 16) {
    {
      float4 ra = *reinterpret_cast<const float4*>(A + (size_t)(m0 + lm) * DM + k0 + lk);
      As[lk + 0][lm] = ra.x; As[lk + 1][lm] = ra.y;
      As[lk + 2][lm] = ra.z; As[lk + 3][lm] = ra.w;
      float4 rb = *reinterpret_cast<const float4*>(W + (size_t)(n0 + lm) * DM + k0 + lk);
      Bs[lk + 0][lm] = rb.x; Bs[lk + 1][lm] = rb.y;
      Bs[lk + 2][lm] = rb.z; Bs[lk + 3][lm] = rb.w;
    }
    __syncthreads();
#pragma unroll
    for (int k = 0; k < 16; k++) {
      float4 av = *reinterpret_cast<const float4*>(&As[k][ty * 4]);
      float4 bv = *reinterpret_cast<const float4*>(&Bs[k][tx * 4]);
      float a_[4] = {av.x, av.y, av.z, av.w};
      float b_[4] = {bv.x, bv.y, bv.z, bv.w};
#pragma unroll
      for (int i = 0; i < 4; i++)
#pragma unroll
        for (int j = 0; j < 4; j++) acc[i][j] += a_[i] * b_[j];
    }
    __syncthreads();
  }
#pragma unroll
  for (int i = 0; i < 4; i++) {
    const int r = m0 + ty * 4 + i;
#pragma unroll
    for (int j = 0; j < 4; j++) {
      const int o = n0 + tx * 4 + j;
      if (split) {
        const int bb = r >> 11, ss = r & 2047, hh = o >> 6, dd = o & 63;
        C[(((size_t)(bb * NH + hh)) * S_LEN + ss) * DK + dd] = acc[i][j];
      } else {
        C[(size_t)r * DM + o] = acc[i][j];
      }
    }
  }
}

// -------- Fused attention: scores -> softmax -> write attn -> PV -> ctx --------
// Block: 256 threads, 4 q-rows of one (b,h). Grid: (512, 8, 4).
// K/V staged transposed in LDS ([d][j], stride 65 -> conflict-free).
__global__ __launch_bounds__(256) void attn_kernel(const float* __restrict__ qh,
    const float* __restrict__ kh, const float* __restrict__ vh,
    float* __restrict__ attn, float* __restrict__ ctx) {
  __shared__ float qs[4][64];
  __shared__ float kt[64][65];
  __shared__ float pr[4][S_LEN];
  __shared__ float red[4][4][64];
  const int t = threadIdx.x;
  const int b = blockIdx.z, h = blockIdx.y, r0 = blockIdx.x * 4;
  const size_t base = ((size_t)(b * NH + h)) * S_LEN * DK;
  {
    const int i = t >> 6, d = t & 63;
    qs[i][d] = qh[base + (size_t)(r0 + i) * DK + d];
  }
  __syncthreads();
  const int jj16 = t >> 4;       // 0..15
  const int dc   = (t & 15) * 4; // 0..60
  // ---- scores ----
  for (int jt = 0; jt < 32; ++jt) {
    const int j0 = jt * 64;
#pragma unroll
    for (int p = 0; p < 4; ++p) {
      const int jj = p * 16 + jj16;
      float4 r = *reinterpret_cast<const float4*>(kh + base + (size_t)(j0 + jj) * DK + dc);
      kt[dc + 0][jj] = r.x; kt[dc + 1][jj] = r.y;
      kt[dc + 2][jj] = r.z; kt[dc + 3][jj] = r.w;
    }
    __syncthreads();
    const int i0 = t >> 6, j = t & 63;
    float a0 = 0.f;
#pragma unroll 8
    for (int d = 0; d < 64; ++d) a0 += qs[i0][d] * kt[d][j];
    pr[i0][j0 + j] = a0 * 0.125f;
    __syncthreads();
  }
  // ---- softmax + attn write ----
  {
    const int i = t >> 6, lane = t & 63;
    float m = -1e30f;
    for (int j = lane; j < S_LEN; j += 64) m = fmaxf(m, pr[i][j]);
#pragma unroll
    for (int mm = 32; mm > 0; mm >>= 1) m = fmaxf(m, __shfl_xor(m, mm, 64));
    float s = 0.f;
    for (int j = lane; j < S_LEN; j += 64) {
      const float e = __expf(pr[i][j] - m);
      pr[i][j] = e; s += e;
    }
#pragma unroll
    for (int mm = 32; mm > 0; mm >>= 1) s += __shfl_xor(s, mm, 64);
    const float inv = 1.f / s;
    float* arow = attn + (((size_t)(b * NH + h)) * S_LEN + (r0 + i)) * S_LEN;
    for (int j = lane; j < S_LEN; j += 64) {
      const float p = pr[i][j] * inv;
      pr[i][j] = p;
      arow[j] = p;
    }
  }
  __syncthreads();
  // ---- PV ----
  const int d = t & 63, slice = t >> 6;
  float acc[4] = {0.f, 0.f, 0.f, 0.f};
  for (int jt = 0; jt < 32; ++jt) {
    const int j0 = jt * 64;
#pragma unroll
    for (int p = 0; p < 4; ++p) {
      const int jj = p * 16 + jj16;
      float4 r = *reinterpret_cast<const float4*>(vh + base + (size_t)(j0 + jj) * DK + dc);
      kt[dc + 0][jj] = r.x; kt[dc + 1][jj] = r.y;
      kt[dc + 2][jj] = r.z; kt[dc + 3][jj] = r.w;
    }
    __syncthreads();
#pragma unroll 4
    for (int jj2 = 0; jj2 < 16; ++jj2) {
      const int jj = slice * 16 + jj2;
      const float vv = kt[d][jj];
      acc[0] += pr[0][j0 + jj] * vv;
      acc[1] += pr[1][j0 + jj] * vv;
      acc[2] += pr[2][j0 + jj] * vv;
      acc[3] += pr[3][j0 + jj] * vv;
    }
    __syncthreads();
  }
#pragma unroll
  for (int i = 0; i < 4; i++) red[slice][i][d] = acc[i];
  __syncthreads();
  {
    const int i = t >> 6, dd = t & 63;
    const float v = red[0][i][dd] + red[1][i][dd] + red[2][i][dd] + red[3][i][dd];
    ctx[((size_t)b * S_LEN + r0 + i) * DM + h * DK + dd] = v;
  }
}

extern "C" void kernel_launch(void* const* d_in, const int* in_sizes, int n_in,
                              void* d_out, int out_size, void* d_ws, size_t ws_size,
                              hipStream_t stream) {
  const float* q   = (const float*)d_in[0];
  const float* k   = (const float*)d_in[1];
  const float* v   = (const float*)d_in[2];
  const float* Wq  = (const float*)d_in[3];
  const float* Wk  = (const float*)d_in[4];
  const float* Wv  = (const float*)d_in[5];
  const float* Wfc = (const float*)d_in[6];
  const float* g   = (const float*)d_in[7];
  const float* bb  = (const float*)d_in[8];

  float* out  = (float*)d_out;
  const size_t NE = (size_t)4 * S_LEN * DM;  // 4,194,304 elements
  float* attn = out + NE;                    // output 1 follows output 0

  // Workspace (fp32): 3 buffers x 16.8 MB = 50.3 MB.
  float* buf0 = (float*)d_ws;        // LN scratch, later ctx
  float* buf1 = buf0 + NE;           // qh, later LN(ctx)
  float* buf2 = buf0 + 2 * NE;       // kh
  float* vhb  = out;                 // vh staged in out0 region (dead until final GEMM)

  ln_kernel<<<2048, 256, 0, stream>>>(q, buf0, g, bb);
  gemm_bt<<<dim3(128, 8), 256, 0, stream>>>(buf0, Wq, buf1, 1);

  ln_kernel<<<2048, 256, 0, stream>>>(k, buf0, g, bb);
  gemm_bt<<<dim3(128, 8), 256, 0, stream>>>(buf0, Wk, buf2, 1);

  ln_kernel<<<2048, 256, 0, stream>>>(v, buf0, g, bb);
  gemm_bt<<<dim3(128, 8), 256, 0, stream>>>(buf0, Wv, vhb, 1);

  attn_kernel<<<dim3(512, 8, 4), 256, 0, stream>>>(buf1, buf2, vhb, attn, buf0);

  ln_kernel<<<2048, 256, 0, stream>>>(buf0, buf1, g, bb);
  gemm_bt<<<dim3(128, 8), 256, 0, stream>>>(buf1, Wfc, out, 0);
}